// Round 12
// baseline (357.633 us; speedup 1.0000x reference)
//
#include <hip/hip_runtime.h>

#define NEG 0.2f
typedef unsigned short u16;
typedef __bf16 bf8 __attribute__((ext_vector_type(8)));
typedef float f4 __attribute__((ext_vector_type(4)));
typedef u16 u16x8 __attribute__((ext_vector_type(8)));

// ---- workspace layout (in floats) ----
#define OFF_P16   0ull                        // u16 [25000][512]: [0:256)=ni, [256:512)=nj (bf16)
#define SZ_P16    (25000ull*256ull)
#define OFF_PM16  (OFF_P16 + SZ_P16)          // u16 [25000][128] msg-part (bf16)
#define SZ_PM16   (25000ull*64ull)
#define OFF_BCF   (OFF_PM16 + SZ_PM16)        // u16[81920] MFMA-frag-packed bcat
#define SZ_BCF    40960ull
#define OFF_BTOT  (OFF_BCF + SZ_BCF)
#define SZ_BTOT   256ull
#define OFF_DEN   (OFF_BTOT + SZ_BTOT)        // (zeroed) denom [25000][2]
#define SZ_DEN    (2ull*25000ull)
#define OFF_AGG   (OFF_DEN + SZ_DEN)          // (zeroed) unnormalized agg
#define SZ_AGG    (25000ull*128ull)
#define OFF_CNT   (OFF_AGG + SZ_AGG)          // (zeroed)
#define SZ_CNT    25000ull
#define OFF_CUR   (OFF_CNT + SZ_CNT)
#define SZ_CUR    25000ull
#define OFF_PERM  (OFF_CUR + SZ_CUR)
#define SZ_PERM   400000ull
#define OFF_DST   (OFF_PERM + SZ_PERM)
#define SZ_DST    400000ull
#define OFF_SRC   (OFF_DST + SZ_DST)
#define SZ_SRC    400000ull
#define OFF_EWF   (OFF_SRC + SZ_SRC)          // u16[16384] MFMA-frag-packed e_W
#define SZ_EWF    8192ull
#define OFF_MWF   (OFF_EWF + SZ_EWF)          // u16[8192] MFMA-frag-packed msg_W edge half
#define SZ_MWF    4096ull

__device__ __forceinline__ u16 f2b(float f) {
    unsigned u = __float_as_uint(f);
    return (u16)((u + 0x7FFFu + ((u >> 16) & 1u)) >> 16);
}
__device__ __forceinline__ float b2f(u16 v) {
    return __uint_as_float(((unsigned)v) << 16);
}
__device__ __forceinline__ bf8 pack8(float4 a, float4 b) {
    union { u16 u[8]; bf8 v; } x;
    x.u[0] = f2b(a.x); x.u[1] = f2b(a.y); x.u[2] = f2b(a.z); x.u[3] = f2b(a.w);
    x.u[4] = f2b(b.x); x.u[5] = f2b(b.y); x.u[6] = f2b(b.z); x.u[7] = f2b(b.w);
    return x.v;
}

// ---- K0: frag-pack bcat (ni|nj|msg), e_W, msg_W-edge-half; total bias ----
__global__ void k_prep(const float* __restrict__ niW, const float* __restrict__ njW,
                       const float* __restrict__ msgW, const float* __restrict__ eW,
                       const float* __restrict__ nib, const float* __restrict__ njb,
                       const float* __restrict__ eb,
                       u16* __restrict__ bcf, float* __restrict__ btot,
                       u16* __restrict__ ewfrag, u16* __restrict__ msgfrag) {
    int idx = blockIdx.x * 256 + threadIdx.x;
    if (idx < 81920) {   // bcat frags: 40 col-blocks x 4 k-steps (K=128)
        int fi = idx >> 9;
        int ln = (idx >> 3) & 63, i = idx & 7;
        int cb = fi >> 2, s = fi & 3;
        int k = s * 32 + ((ln >> 4) << 3) + i;
        int col = cb * 16 + (ln & 15);
        float v = (col < 256) ? niW[k * 256 + col]
                : (col < 512) ? njW[k * 256 + (col - 256)]
                              : msgW[k * 128 + (col - 512)];
        bcf[idx] = f2b(v);
    }
    if (idx < 16384) {   // e_W frags: 16 col-blocks x 2 k-steps (K=64)
        int c = idx >> 10, s = (idx >> 9) & 1, ln = (idx >> 3) & 63, i = idx & 7;
        int k = s * 32 + ((ln >> 4) << 3) + i;
        int col = c * 16 + (ln & 15);
        ewfrag[idx] = f2b(eW[k * 256 + col]);
    }
    if (idx < 8192) {    // msg_W edge-half frags: 8 col-blocks x 2 k-steps
        int c = idx >> 10, s = (idx >> 9) & 1, ln = (idx >> 3) & 63, i = idx & 7;
        int k = s * 32 + ((ln >> 4) << 3) + i;
        int col = c * 16 + (ln & 15);
        msgfrag[idx] = f2b(msgW[(128 + k) * 128 + col]);
    }
    if (idx < 256) btot[idx] = nib[idx] + njb[idx] + eb[idx];
}

// shared inner GEMM tile (f32 VALU) — used by k_out only
__device__ __forceinline__ void gemm_tile(const float* Al, int astride, int acol0,
                                          const float* Bl, int trow, int tcol,
                                          float acc[4][8]) {
    for (int k4 = 0; k4 < 64; k4 += 4) {
        float ar[4][4];
#pragma unroll
        for (int r = 0; r < 4; ++r)
            *(float4*)ar[r] = *(const float4*)&Al[(trow * 4 + r) * astride + acol0 + k4];
#pragma unroll
        for (int kk = 0; kk < 4; ++kk) {
            float4 b0 = *(const float4*)&Bl[(k4 + kk) * 128 + tcol * 8];
            float4 b1 = *(const float4*)&Bl[(k4 + kk) * 128 + tcol * 8 + 4];
            float bv[8] = {b0.x, b0.y, b0.z, b0.w, b1.x, b1.y, b1.z, b1.w};
#pragma unroll
            for (int r = 0; r < 4; ++r) {
                float av = ar[r][kk];
#pragma unroll
                for (int j = 0; j < 8; ++j) acc[r][j] = fmaf(av, bv[j], acc[r][j]);
            }
        }
    }
}

// ---- K1: pre = nf @ bcat via bf16 MFMA; one wave = 16 nodes x 640 cols ----
__global__ __launch_bounds__(256) void k_node_pre(const float* __restrict__ nf,
                                                  const u16* __restrict__ bcf,
                                                  u16* __restrict__ pre16,
                                                  u16* __restrict__ premsg16) {
    int t = threadIdx.x, w = t >> 6, l = t & 63;
    int n0 = blockIdx.x * 64 + w * 16;
    int rsel = l & 15, kb = l >> 4;
    int nA = n0 + rsel;
    size_t nAc = (nA < 25000) ? (size_t)nA : 24999;
    const float* ap = &nf[nAc * 128 + kb * 8];
    bf8 a[4];
#pragma unroll
    for (int s = 0; s < 4; ++s) {
        float4 x = *(const float4*)&ap[s * 32];
        float4 y = *(const float4*)&ap[s * 32 + 4];
        a[s] = pack8(x, y);
    }
    int nC = n0 + kb * 4;
#pragma unroll 4
    for (int cb = 0; cb < 40; ++cb) {
        f4 acc = {0.f, 0.f, 0.f, 0.f};
#pragma unroll
        for (int s = 0; s < 4; ++s) {
            bf8 b = *(const bf8*)&bcf[(size_t)((cb * 4 + s) * 64 + l) * 8];
            acc = __builtin_amdgcn_mfma_f32_16x16x32_bf16(a[s], b, acc, 0, 0, 0);
        }
#pragma unroll
        for (int r = 0; r < 4; ++r) {
            int nn = nC + r;
            if (nn < 25000) {
                if (cb < 32) pre16[(size_t)nn * 512 + cb * 16 + rsel] = f2b(acc[r]);
                else premsg16[(size_t)nn * 128 + (cb - 32) * 16 + rsel] = f2b(acc[r]);
            }
        }
    }
}

// ---- K2a: histogram of dst ----
__global__ void k_hist(const int* __restrict__ eidx, int* __restrict__ count) {
    int e = blockIdx.x * 256 + threadIdx.x;
    if (e < 400000) atomicAdd(&count[eidx[e]], 1);
}

// ---- K2b: exclusive scan (single block) count -> cursor ----
__global__ __launch_bounds__(1024) void k_scan(const int* __restrict__ count,
                                               int* __restrict__ cursor) {
    __shared__ int sums[1024];
    int t = threadIdx.x;
    int base = t * 25;
    int v[25];
    int local = 0;
#pragma unroll
    for (int i = 0; i < 25; ++i) {
        int idx = base + i;
        int c = (idx < 25000) ? count[idx] : 0;
        v[i] = local;
        local += c;
    }
    sums[t] = local;
    __syncthreads();
    for (int off = 1; off < 1024; off <<= 1) {
        int x = (t >= off) ? sums[t - off] : 0;
        __syncthreads();
        sums[t] += x;
        __syncthreads();
    }
    int prefix = (t == 0) ? 0 : sums[t - 1];
#pragma unroll
    for (int i = 0; i < 25; ++i) {
        int idx = base + i;
        if (idx < 25000) cursor[idx] = prefix + v[i];
    }
}

// ---- K2c: scatter edge ids + dst/src into dst-sorted order ----
__global__ void k_scatter(const int* __restrict__ eidx, int* __restrict__ cursor,
                          int* __restrict__ perm, int* __restrict__ dsts,
                          int* __restrict__ srcs) {
    int e = blockIdx.x * 256 + threadIdx.x;
    if (e < 400000) {
        int d = eidx[e];
        int p = atomicAdd(&cursor[d], 1);
        perm[p] = e;
        dsts[p] = d;
        srcs[p] = eidx[400000 + e];
    }
}

// ---- K3: FUSED logits + exp + denom + messages + segmented agg  ----
// No max subtraction: ex = exp(logit) directly; agg accumulates ex-weighted
// messages; k_out divides by denom. ef loaded & packed ONCE; attention weight
// never leaves registers (butterfly leaves reduced logit on all 16 lanes).
__global__ __launch_bounds__(256) void k_edge_fused(
        const float* __restrict__ ef, const int* __restrict__ perm,
        const int* __restrict__ dsts, const int* __restrict__ srcs,
        const u16* __restrict__ ewfrag, const u16* __restrict__ msgfrag,
        const u16* __restrict__ pre16, const u16* __restrict__ premsg16,
        const float* __restrict__ btot, const float* __restrict__ aproj,
        float* __restrict__ denom, float* __restrict__ agg) {
    __shared__ float Msg[64 * 132];
    __shared__ int eperm[64], dstl[64], srcl[64];
    int t = threadIdx.x;
    int w = t >> 6, l = t & 63;
    int p0 = blockIdx.x * 64;
    int row = l & 15, kb = l >> 4;

    if (t < 64) {
        eperm[t] = perm[p0 + t];
        dstl[t] = dsts[p0 + t];
        srcl[t] = srcs[p0 + t];
    }
    __syncthreads();

    int ea = eperm[w * 16 + row];
    const float* ap = &ef[(size_t)ea * 64 + kb * 8];
    float4 a00 = *(const float4*)ap;
    float4 a01 = *(const float4*)(ap + 4);
    float4 a10 = *(const float4*)(ap + 32);
    float4 a11 = *(const float4*)(ap + 36);
    bf8 a0 = pack8(a00, a01), a1 = pack8(a10, a11);

    int ed[4], es[4];
#pragma unroll
    for (int r = 0; r < 4; ++r) {
        int i4 = w * 16 + kb * 4 + r;
        ed[r] = dstl[i4];
        es[r] = srcl[i4];
    }

    // ---- phase 1: logits (R9-proven shape) ----
    float part0[4] = {0.f, 0.f, 0.f, 0.f}, part1[4] = {0.f, 0.f, 0.f, 0.f};
#pragma unroll
    for (int c = 0; c < 16; ++c) {
        bf8 b0 = *(const bf8*)&ewfrag[(size_t)((c * 2 + 0) * 64 + l) * 8];
        bf8 b1 = *(const bf8*)&ewfrag[(size_t)((c * 2 + 1) * 64 + l) * 8];
        f4 acc = {0.f, 0.f, 0.f, 0.f};
        acc = __builtin_amdgcn_mfma_f32_16x16x32_bf16(a0, b0, acc, 0, 0, 0);
        acc = __builtin_amdgcn_mfma_f32_16x16x32_bf16(a1, b1, acc, 0, 0, 0);
        int col = c * 16 + row;
        float bt = btot[col], apj = aproj[col];
#pragma unroll
        for (int r = 0; r < 4; ++r) {
            float pi = b2f(pre16[(size_t)ed[r] * 512 + col]);
            float pj = b2f(pre16[(size_t)es[r] * 512 + 256 + col]);
            float hid = acc[r] + pi + pj + bt;
            hid = hid >= 0.f ? hid : NEG * hid;
            if (c < 8) part0[r] = fmaf(hid, apj, part0[r]);
            else       part1[r] = fmaf(hid, apj, part1[r]);
        }
    }
#pragma unroll
    for (int m = 1; m < 16; m <<= 1) {
#pragma unroll
        for (int r = 0; r < 4; ++r) {
            part0[r] += __shfl_xor(part0[r], m);
            part1[r] += __shfl_xor(part1[r], m);
        }
    }
    // unnormalized weights, in-register on every lane
    float ex0[4], ex1[4];
#pragma unroll
    for (int r = 0; r < 4; ++r) {
        ex0[r] = __expf(part0[r]);
        ex1[r] = __expf(part1[r]);
    }
    if (row == 0) {
#pragma unroll
        for (int r = 0; r < 4; ++r) {
            atomicAdd(&denom[ed[r] * 2 + 0], ex0[r]);
            atomicAdd(&denom[ed[r] * 2 + 1], ex1[r]);
        }
    }

    // ---- phase 2: messages, ef frags reused, weights from registers ----
#pragma unroll
    for (int c = 0; c < 8; ++c) {
        bf8 b0 = *(const bf8*)&msgfrag[(size_t)((c * 2 + 0) * 64 + l) * 8];
        bf8 b1 = *(const bf8*)&msgfrag[(size_t)((c * 2 + 1) * 64 + l) * 8];
        f4 acc = {0.f, 0.f, 0.f, 0.f};
        acc = __builtin_amdgcn_mfma_f32_16x16x32_bf16(a0, b0, acc, 0, 0, 0);
        acc = __builtin_amdgcn_mfma_f32_16x16x32_bf16(a1, b1, acc, 0, 0, 0);
        int col = c * 16 + row;             // msg col 0..127; head = c>>2
#pragma unroll
        for (int r = 0; r < 4; ++r) {
            int i4 = w * 16 + kb * 4 + r;
            float m = acc[r] + b2f(premsg16[(size_t)es[r] * 128 + col]);
            float wm = ((c < 4) ? ex0[r] : ex1[r]) * m;
            Msg[i4 * 132 + col] = wm;
        }
    }
    __syncthreads();

    // segmented reduction over sorted dst; one atomic per (run, col)
    int c = t & 127, half = t >> 7;
    int r0 = half * 32, r1 = r0 + 32;
    int cur = dstl[r0];
    float sum = 0.f;
    for (int r = r0; r < r1; ++r) {
        int d = dstl[r];
        if (d != cur) {
            atomicAdd(&agg[(size_t)cur * 128 + c], sum);
            sum = 0.f;
            cur = d;
        }
        sum += Msg[r * 132 + c];
    }
    atomicAdd(&agg[(size_t)cur * 128 + c], sum);
}

// ---- K6: out = (agg/denom + msg_b*[deg>0]) @ out_W + out_b ----
__global__ __launch_bounds__(256) void k_out(
        const float* __restrict__ agg, const float* __restrict__ denom,
        const int* __restrict__ count,
        const float* __restrict__ msgb, const float* __restrict__ outW,
        const float* __restrict__ outb, float* __restrict__ out) {
    __shared__ float Al[64 * 128];
    __shared__ float Bl[64 * 128];
    int t = threadIdx.x, n0 = blockIdx.x * 64;
    int trow = t >> 4, tcol = t & 15;
#pragma unroll
    for (int q = 0; q < 8; ++q) {
        int g = t + 256 * q;
        int i = g >> 5, k4 = (g & 31) * 4;
        int n = n0 + i;
        float4 v = make_float4(0.f, 0.f, 0.f, 0.f);
        if (n < 25000 && count[n] > 0) {
            v = *(const float4*)&agg[(size_t)n * 128 + k4];
            float invd = 1.f / denom[n * 2 + (k4 >> 6)];
            float4 mb = *(const float4*)&msgb[k4];
            v.x = v.x * invd + mb.x; v.y = v.y * invd + mb.y;
            v.z = v.z * invd + mb.z; v.w = v.w * invd + mb.w;
        }
        *(float4*)&Al[i * 128 + k4] = v;
    }
    float acc[4][8] = {};
    for (int kh = 0; kh < 2; ++kh) {
        __syncthreads();
#pragma unroll
        for (int q = 0; q < 8; ++q) {
            int g = t + 256 * q;
            int k = g >> 5, c4 = (g & 31) * 4;
            *(float4*)&Bl[k * 128 + c4] = *(const float4*)&outW[(kh * 64 + k) * 128 + c4];
        }
        __syncthreads();
        gemm_tile(Al, 128, kh * 64, Bl, trow, tcol, acc);
    }
    float ob[8];
    *(float4*)ob = *(const float4*)&outb[tcol * 8];
    *(float4*)(ob + 4) = *(const float4*)&outb[tcol * 8 + 4];
#pragma unroll
    for (int r = 0; r < 4; ++r) {
        int n = n0 + trow * 4 + r;
        if (n < 25000) {
            *(float4*)&out[(size_t)n * 128 + tcol * 8] =
                make_float4(acc[r][0] + ob[0], acc[r][1] + ob[1], acc[r][2] + ob[2], acc[r][3] + ob[3]);
            *(float4*)&out[(size_t)n * 128 + tcol * 8 + 4] =
                make_float4(acc[r][4] + ob[4], acc[r][5] + ob[5], acc[r][6] + ob[6], acc[r][7] + ob[7]);
        }
    }
}

extern "C" void kernel_launch(void* const* d_in, const int* in_sizes, int n_in,
                              void* d_out, int out_size, void* d_ws, size_t ws_size,
                              hipStream_t stream) {
    const float* nf    = (const float*)d_in[0];
    const float* ef    = (const float*)d_in[1];
    const int*   eidx  = (const int*)d_in[2];
    const float* niW   = (const float*)d_in[3];
    const float* nib   = (const float*)d_in[4];
    const float* njW   = (const float*)d_in[5];
    const float* njb   = (const float*)d_in[6];
    const float* eW    = (const float*)d_in[7];
    const float* eb    = (const float*)d_in[8];
    const float* aproj = (const float*)d_in[9];
    const float* msgW  = (const float*)d_in[10];
    const float* msgb  = (const float*)d_in[11];
    const float* outW  = (const float*)d_in[12];
    const float* outb  = (const float*)d_in[13];

    float* ws = (float*)d_ws;
    u16*   pre16     = (u16*)(ws + OFF_P16);
    u16*   premsg16  = (u16*)(ws + OFF_PM16);
    u16*   bcf       = (u16*)(ws + OFF_BCF);
    float* btot      = ws + OFF_BTOT;
    float* denom     = ws + OFF_DEN;
    float* agg       = ws + OFF_AGG;
    int*   count     = (int*)(ws + OFF_CNT);
    int*   cursor    = (int*)(ws + OFF_CUR);
    int*   perm      = (int*)(ws + OFF_PERM);
    int*   dsts      = (int*)(ws + OFF_DST);
    int*   srcs      = (int*)(ws + OFF_SRC);
    u16*   ewfrag    = (u16*)(ws + OFF_EWF);
    u16*   msgfrag   = (u16*)(ws + OFF_MWF);

    // zero denom + agg + count (contiguous)
    hipMemsetAsync(ws + OFF_DEN, 0, (size_t)(SZ_DEN + SZ_AGG + SZ_CNT) * 4, stream);

    k_prep<<<320, 256, 0, stream>>>(niW, njW, msgW, eW, nib, njb, eb,
                                    bcf, btot, ewfrag, msgfrag);
    k_node_pre<<<391, 256, 0, stream>>>(nf, bcf, pre16, premsg16);
    k_hist<<<1563, 256, 0, stream>>>(eidx, count);
    k_scan<<<1, 1024, 0, stream>>>(count, cursor);
    k_scatter<<<1563, 256, 0, stream>>>(eidx, cursor, perm, dsts, srcs);
    k_edge_fused<<<6250, 256, 0, stream>>>(ef, perm, dsts, srcs, ewfrag, msgfrag,
                                           pre16, premsg16, btot, aproj, denom, agg);
    k_out<<<391, 256, 0, stream>>>(agg, denom, count, msgb, outW, outb, (float*)d_out);
}

// Round 13
// 319.759 us; speedup vs baseline: 1.1184x; 1.1184x over previous
//
#include <hip/hip_runtime.h>

#define NEG 0.2f
typedef unsigned short u16;
typedef __bf16 bf8 __attribute__((ext_vector_type(8)));
typedef float f4 __attribute__((ext_vector_type(4)));
typedef u16 u16x8 __attribute__((ext_vector_type(8)));

// ---- workspace layout (in floats) ----
#define OFF_P16   0ull                        // u16 [25000][512]: [0:256)=ni, [256:512)=nj (bf16)
#define SZ_P16    (25000ull*256ull)
#define OFF_PM16  (OFF_P16 + SZ_P16)          // u16 [25000][128] msg-part (bf16)
#define SZ_PM16   (25000ull*64ull)
#define OFF_BCF   (OFF_PM16 + SZ_PM16)        // u16[81920] MFMA-frag-packed bcat
#define SZ_BCF    40960ull
#define OFF_BTOT  (OFF_BCF + SZ_BCF)
#define SZ_BTOT   256ull
#define OFF_EX    (OFF_BTOT + SZ_BTOT)        // ex (unnormalized attn), SORTED space [p][2]
#define SZ_EX     (2ull*400000ull)
#define OFF_DEN   (OFF_EX + SZ_EX)            // (zeroed) denom [25000][2]
#define SZ_DEN    (2ull*25000ull)
#define OFF_AGG   (OFF_DEN + SZ_DEN)          // (zeroed)
#define SZ_AGG    (25000ull*128ull)
#define OFF_CNT   (OFF_AGG + SZ_AGG)          // (zeroed)
#define SZ_CNT    25000ull
#define OFF_CUR   (OFF_CNT + SZ_CNT)
#define SZ_CUR    25000ull
#define OFF_PERM  (OFF_CUR + SZ_CUR)
#define SZ_PERM   400000ull
#define OFF_DST   (OFF_PERM + SZ_PERM)
#define SZ_DST    400000ull
#define OFF_SRC   (OFF_DST + SZ_DST)
#define SZ_SRC    400000ull
#define OFF_EWF   (OFF_SRC + SZ_SRC)          // u16[16384] MFMA-frag-packed e_W
#define SZ_EWF    8192ull
#define OFF_MWF   (OFF_EWF + SZ_EWF)          // u16[8192] MFMA-frag-packed msg_W edge half
#define SZ_MWF    4096ull

__device__ __forceinline__ u16 f2b(float f) {
    unsigned u = __float_as_uint(f);
    return (u16)((u + 0x7FFFu + ((u >> 16) & 1u)) >> 16);
}
__device__ __forceinline__ float b2f(u16 v) {
    return __uint_as_float(((unsigned)v) << 16);
}
__device__ __forceinline__ bf8 pack8(float4 a, float4 b) {
    union { u16 u[8]; bf8 v; } x;
    x.u[0] = f2b(a.x); x.u[1] = f2b(a.y); x.u[2] = f2b(a.z); x.u[3] = f2b(a.w);
    x.u[4] = f2b(b.x); x.u[5] = f2b(b.y); x.u[6] = f2b(b.z); x.u[7] = f2b(b.w);
    return x.v;
}

// ---- K0: frag-pack bcat (ni|nj|msg), e_W, msg_W-edge-half; total bias ----
__global__ void k_prep(const float* __restrict__ niW, const float* __restrict__ njW,
                       const float* __restrict__ msgW, const float* __restrict__ eW,
                       const float* __restrict__ nib, const float* __restrict__ njb,
                       const float* __restrict__ eb,
                       u16* __restrict__ bcf, float* __restrict__ btot,
                       u16* __restrict__ ewfrag, u16* __restrict__ msgfrag) {
    int idx = blockIdx.x * 256 + threadIdx.x;
    if (idx < 81920) {   // bcat frags: 40 col-blocks x 4 k-steps (K=128)
        int fi = idx >> 9;
        int ln = (idx >> 3) & 63, i = idx & 7;
        int cb = fi >> 2, s = fi & 3;
        int k = s * 32 + ((ln >> 4) << 3) + i;
        int col = cb * 16 + (ln & 15);
        float v = (col < 256) ? niW[k * 256 + col]
                : (col < 512) ? njW[k * 256 + (col - 256)]
                              : msgW[k * 128 + (col - 512)];
        bcf[idx] = f2b(v);
    }
    if (idx < 16384) {   // e_W frags: 16 col-blocks x 2 k-steps (K=64)
        int c = idx >> 10, s = (idx >> 9) & 1, ln = (idx >> 3) & 63, i = idx & 7;
        int k = s * 32 + ((ln >> 4) << 3) + i;
        int col = c * 16 + (ln & 15);
        ewfrag[idx] = f2b(eW[k * 256 + col]);
    }
    if (idx < 8192) {    // msg_W edge-half frags: 8 col-blocks x 2 k-steps
        int c = idx >> 10, s = (idx >> 9) & 1, ln = (idx >> 3) & 63, i = idx & 7;
        int k = s * 32 + ((ln >> 4) << 3) + i;
        int col = c * 16 + (ln & 15);
        msgfrag[idx] = f2b(msgW[(128 + k) * 128 + col]);
    }
    if (idx < 256) btot[idx] = nib[idx] + njb[idx] + eb[idx];
}

// shared inner GEMM tile (f32 VALU) — used by k_out only
__device__ __forceinline__ void gemm_tile(const float* Al, int astride, int acol0,
                                          const float* Bl, int trow, int tcol,
                                          float acc[4][8]) {
    for (int k4 = 0; k4 < 64; k4 += 4) {
        float ar[4][4];
#pragma unroll
        for (int r = 0; r < 4; ++r)
            *(float4*)ar[r] = *(const float4*)&Al[(trow * 4 + r) * astride + acol0 + k4];
#pragma unroll
        for (int kk = 0; kk < 4; ++kk) {
            float4 b0 = *(const float4*)&Bl[(k4 + kk) * 128 + tcol * 8];
            float4 b1 = *(const float4*)&Bl[(k4 + kk) * 128 + tcol * 8 + 4];
            float bv[8] = {b0.x, b0.y, b0.z, b0.w, b1.x, b1.y, b1.z, b1.w};
#pragma unroll
            for (int r = 0; r < 4; ++r) {
                float av = ar[r][kk];
#pragma unroll
                for (int j = 0; j < 8; ++j) acc[r][j] = fmaf(av, bv[j], acc[r][j]);
            }
        }
    }
}

// ---- K1: pre = nf @ bcat via bf16 MFMA; one wave = 16 nodes x 640 cols ----
__global__ __launch_bounds__(256) void k_node_pre(const float* __restrict__ nf,
                                                  const u16* __restrict__ bcf,
                                                  u16* __restrict__ pre16,
                                                  u16* __restrict__ premsg16) {
    int t = threadIdx.x, w = t >> 6, l = t & 63;
    int n0 = blockIdx.x * 64 + w * 16;
    int rsel = l & 15, kb = l >> 4;
    int nA = n0 + rsel;
    size_t nAc = (nA < 25000) ? (size_t)nA : 24999;
    const float* ap = &nf[nAc * 128 + kb * 8];
    bf8 a[4];
#pragma unroll
    for (int s = 0; s < 4; ++s) {
        float4 x = *(const float4*)&ap[s * 32];
        float4 y = *(const float4*)&ap[s * 32 + 4];
        a[s] = pack8(x, y);
    }
    int nC = n0 + kb * 4;
#pragma unroll 4
    for (int cb = 0; cb < 40; ++cb) {
        f4 acc = {0.f, 0.f, 0.f, 0.f};
#pragma unroll
        for (int s = 0; s < 4; ++s) {
            bf8 b = *(const bf8*)&bcf[(size_t)((cb * 4 + s) * 64 + l) * 8];
            acc = __builtin_amdgcn_mfma_f32_16x16x32_bf16(a[s], b, acc, 0, 0, 0);
        }
#pragma unroll
        for (int r = 0; r < 4; ++r) {
            int nn = nC + r;
            if (nn < 25000) {
                if (cb < 32) pre16[(size_t)nn * 512 + cb * 16 + rsel] = f2b(acc[r]);
                else premsg16[(size_t)nn * 128 + (cb - 32) * 16 + rsel] = f2b(acc[r]);
            }
        }
    }
}

// ---- K2a: histogram of dst ----
__global__ void k_hist(const int* __restrict__ eidx, int* __restrict__ count) {
    int e = blockIdx.x * 256 + threadIdx.x;
    if (e < 400000) atomicAdd(&count[eidx[e]], 1);
}

// ---- K2b: exclusive scan (single block) count -> cursor ----
__global__ __launch_bounds__(1024) void k_scan(const int* __restrict__ count,
                                               int* __restrict__ cursor) {
    __shared__ int sums[1024];
    int t = threadIdx.x;
    int base = t * 25;
    int v[25];
    int local = 0;
#pragma unroll
    for (int i = 0; i < 25; ++i) {
        int idx = base + i;
        int c = (idx < 25000) ? count[idx] : 0;
        v[i] = local;
        local += c;
    }
    sums[t] = local;
    __syncthreads();
    for (int off = 1; off < 1024; off <<= 1) {
        int x = (t >= off) ? sums[t - off] : 0;
        __syncthreads();
        sums[t] += x;
        __syncthreads();
    }
    int prefix = (t == 0) ? 0 : sums[t - 1];
#pragma unroll
    for (int i = 0; i < 25; ++i) {
        int idx = base + i;
        if (idx < 25000) cursor[idx] = prefix + v[i];
    }
}

// ---- K2c: scatter edge ids + dst/src into dst-sorted order ----
__global__ void k_scatter(const int* __restrict__ eidx, int* __restrict__ cursor,
                          int* __restrict__ perm, int* __restrict__ dsts,
                          int* __restrict__ srcs) {
    int e = blockIdx.x * 256 + threadIdx.x;
    if (e < 400000) {
        int d = eidx[e];
        int p = atomicAdd(&cursor[d], 1);
        perm[p] = e;
        dsts[p] = d;
        srcs[p] = eidx[400000 + e];
    }
}

// ---- K3: edge logits (R9 shape) + max-free exp + denom (R12-validated) ----
__global__ __launch_bounds__(256) void k_edge_logits(
        const float* __restrict__ ef, const int* __restrict__ perm,
        const int* __restrict__ dsts, const int* __restrict__ srcs,
        const u16* __restrict__ ewfrag, const u16* __restrict__ pre16,
        const float* __restrict__ btot, const float* __restrict__ aproj,
        float* __restrict__ exs, float* __restrict__ denom) {
    __shared__ int eperm[64], dstl[64], srcl[64];
    int t = threadIdx.x;
    int w = t >> 6, l = t & 63;
    int p0 = blockIdx.x * 64;
    int row = l & 15, kb = l >> 4;

    if (t < 64) {
        eperm[t] = perm[p0 + t];
        dstl[t] = dsts[p0 + t];
        srcl[t] = srcs[p0 + t];
    }
    __syncthreads();

    int ea = eperm[w * 16 + row];
    const float* ap = &ef[(size_t)ea * 64 + kb * 8];
    float4 a00 = *(const float4*)ap;
    float4 a01 = *(const float4*)(ap + 4);
    float4 a10 = *(const float4*)(ap + 32);
    float4 a11 = *(const float4*)(ap + 36);
    bf8 a0 = pack8(a00, a01), a1 = pack8(a10, a11);

    int ed[4], es[4];
#pragma unroll
    for (int r = 0; r < 4; ++r) {
        int i4 = w * 16 + kb * 4 + r;
        ed[r] = dstl[i4];
        es[r] = srcl[i4];
    }

    float part0[4] = {0.f, 0.f, 0.f, 0.f}, part1[4] = {0.f, 0.f, 0.f, 0.f};
#pragma unroll
    for (int c = 0; c < 16; ++c) {
        bf8 b0 = *(const bf8*)&ewfrag[(size_t)((c * 2 + 0) * 64 + l) * 8];
        bf8 b1 = *(const bf8*)&ewfrag[(size_t)((c * 2 + 1) * 64 + l) * 8];
        f4 acc = {0.f, 0.f, 0.f, 0.f};
        acc = __builtin_amdgcn_mfma_f32_16x16x32_bf16(a0, b0, acc, 0, 0, 0);
        acc = __builtin_amdgcn_mfma_f32_16x16x32_bf16(a1, b1, acc, 0, 0, 0);
        int col = c * 16 + row;
        float bt = btot[col], apj = aproj[col];
#pragma unroll
        for (int r = 0; r < 4; ++r) {
            float pi = b2f(pre16[(size_t)ed[r] * 512 + col]);
            float pj = b2f(pre16[(size_t)es[r] * 512 + 256 + col]);
            float hid = acc[r] + pi + pj + bt;
            hid = hid >= 0.f ? hid : NEG * hid;
            if (c < 8) part0[r] = fmaf(hid, apj, part0[r]);
            else       part1[r] = fmaf(hid, apj, part1[r]);
        }
    }
#pragma unroll
    for (int m = 1; m < 16; m <<= 1) {
#pragma unroll
        for (int r = 0; r < 4; ++r) {
            part0[r] += __shfl_xor(part0[r], m);
            part1[r] += __shfl_xor(part1[r], m);
        }
    }
    if (row == 0) {
#pragma unroll
        for (int r = 0; r < 4; ++r) {
            int p = p0 + w * 16 + kb * 4 + r;
            float e0 = __expf(part0[r]);
            float e1 = __expf(part1[r]);
            exs[(size_t)p * 2 + 0] = e0;
            exs[(size_t)p * 2 + 1] = e1;
            atomicAdd(&denom[ed[r] * 2 + 0], e0);
            atomicAdd(&denom[ed[r] * 2 + 1], e1);
        }
    }
}

// ---- K5: messages via bf16 MFMA (R9-proven) + bf16 premsg gather + seg reduce ----
__global__ __launch_bounds__(256) void k_messages(
        const float* __restrict__ ef, const int* __restrict__ perm,
        const int* __restrict__ dsts, const int* __restrict__ srcs,
        const u16* __restrict__ msgfrag, const u16* __restrict__ premsg16,
        const float* __restrict__ exs, const float* __restrict__ denom,
        float* __restrict__ agg) {
    __shared__ float Msg[64 * 132];
    __shared__ int dstl[64], srcl[64], eperm[64];
    __shared__ float attl[64][2];
    int t = threadIdx.x;
    int w = t >> 6, l = t & 63;
    int p0 = blockIdx.x * 64;
    int row = l & 15, kb = l >> 4;

    if (t < 64) {
        int p = p0 + t;
        eperm[t] = perm[p];
        int d = dsts[p];
        dstl[t] = d;
        srcl[t] = srcs[p];
        attl[t][0] = exs[(size_t)p * 2 + 0] / denom[d * 2 + 0];
        attl[t][1] = exs[(size_t)p * 2 + 1] / denom[d * 2 + 1];
    }
    __syncthreads();

    int ea = eperm[w * 16 + row];
    const float* apr = &ef[(size_t)ea * 64 + kb * 8];
    float4 a00 = *(const float4*)apr;
    float4 a01 = *(const float4*)(apr + 4);
    float4 a10 = *(const float4*)(apr + 32);
    float4 a11 = *(const float4*)(apr + 36);
    bf8 a0 = pack8(a00, a01), a1 = pack8(a10, a11);

    int esr[4];
    float at0[4], at1[4];
#pragma unroll
    for (int r = 0; r < 4; ++r) {
        int i4 = w * 16 + kb * 4 + r;
        esr[r] = srcl[i4];
        at0[r] = attl[i4][0];
        at1[r] = attl[i4][1];
    }

#pragma unroll
    for (int c = 0; c < 8; ++c) {
        bf8 b0 = *(const bf8*)&msgfrag[(size_t)((c * 2 + 0) * 64 + l) * 8];
        bf8 b1 = *(const bf8*)&msgfrag[(size_t)((c * 2 + 1) * 64 + l) * 8];
        f4 acc = {0.f, 0.f, 0.f, 0.f};
        acc = __builtin_amdgcn_mfma_f32_16x16x32_bf16(a0, b0, acc, 0, 0, 0);
        acc = __builtin_amdgcn_mfma_f32_16x16x32_bf16(a1, b1, acc, 0, 0, 0);
        int col = c * 16 + row;             // msg col 0..127; head = c>>2
#pragma unroll
        for (int r = 0; r < 4; ++r) {
            float m = acc[r] + b2f(premsg16[(size_t)esr[r] * 128 + col]);
            float wm = ((c < 4) ? at0[r] : at1[r]) * m;
            Msg[(w * 16 + kb * 4 + r) * 132 + col] = wm;
        }
    }
    __syncthreads();

    // segmented reduction over sorted dst; one atomic per (run, col)
    int c = t & 127, half = t >> 7;
    int r0 = half * 32, r1 = r0 + 32;
    int cur = dstl[r0];
    float sum = 0.f;
    for (int r = r0; r < r1; ++r) {
        int d = dstl[r];
        if (d != cur) {
            atomicAdd(&agg[(size_t)cur * 128 + c], sum);
            sum = 0.f;
            cur = d;
        }
        sum += Msg[r * 132 + c];
    }
    atomicAdd(&agg[(size_t)cur * 128 + c], sum);
}

// ---- K6: out = (agg + msg_b*[deg>0]) @ out_W + out_b ----
__global__ __launch_bounds__(256) void k_out(
        const float* __restrict__ agg, const int* __restrict__ count,
        const float* __restrict__ msgb, const float* __restrict__ outW,
        const float* __restrict__ outb, float* __restrict__ out) {
    __shared__ float Al[64 * 128];
    __shared__ float Bl[64 * 128];
    int t = threadIdx.x, n0 = blockIdx.x * 64;
    int trow = t >> 4, tcol = t & 15;
#pragma unroll
    for (int q = 0; q < 8; ++q) {
        int g = t + 256 * q;
        int i = g >> 5, k4 = (g & 31) * 4;
        int n = n0 + i;
        float4 v = make_float4(0.f, 0.f, 0.f, 0.f);
        if (n < 25000) {
            v = *(const float4*)&agg[(size_t)n * 128 + k4];
            if (count[n] > 0) {
                float4 mb = *(const float4*)&msgb[k4];
                v.x += mb.x; v.y += mb.y; v.z += mb.z; v.w += mb.w;
            }
        }
        *(float4*)&Al[i * 128 + k4] = v;
    }
    float acc[4][8] = {};
    for (int kh = 0; kh < 2; ++kh) {
        __syncthreads();
#pragma unroll
        for (int q = 0; q < 8; ++q) {
            int g = t + 256 * q;
            int k = g >> 5, c4 = (g & 31) * 4;
            *(float4*)&Bl[k * 128 + c4] = *(const float4*)&outW[(kh * 64 + k) * 128 + c4];
        }
        __syncthreads();
        gemm_tile(Al, 128, kh * 64, Bl, trow, tcol, acc);
    }
    float ob[8];
    *(float4*)ob = *(const float4*)&outb[tcol * 8];
    *(float4*)(ob + 4) = *(const float4*)&outb[tcol * 8 + 4];
#pragma unroll
    for (int r = 0; r < 4; ++r) {
        int n = n0 + trow * 4 + r;
        if (n < 25000) {
            *(float4*)&out[(size_t)n * 128 + tcol * 8] =
                make_float4(acc[r][0] + ob[0], acc[r][1] + ob[1], acc[r][2] + ob[2], acc[r][3] + ob[3]);
            *(float4*)&out[(size_t)n * 128 + tcol * 8 + 4] =
                make_float4(acc[r][4] + ob[4], acc[r][5] + ob[5], acc[r][6] + ob[6], acc[r][7] + ob[7]);
        }
    }
}

extern "C" void kernel_launch(void* const* d_in, const int* in_sizes, int n_in,
                              void* d_out, int out_size, void* d_ws, size_t ws_size,
                              hipStream_t stream) {
    const float* nf    = (const float*)d_in[0];
    const float* ef    = (const float*)d_in[1];
    const int*   eidx  = (const int*)d_in[2];
    const float* niW   = (const float*)d_in[3];
    const float* nib   = (const float*)d_in[4];
    const float* njW   = (const float*)d_in[5];
    const float* njb   = (const float*)d_in[6];
    const float* eW    = (const float*)d_in[7];
    const float* eb    = (const float*)d_in[8];
    const float* aproj = (const float*)d_in[9];
    const float* msgW  = (const float*)d_in[10];
    const float* msgb  = (const float*)d_in[11];
    const float* outW  = (const float*)d_in[12];
    const float* outb  = (const float*)d_in[13];

    float* ws = (float*)d_ws;
    u16*   pre16     = (u16*)(ws + OFF_P16);
    u16*   premsg16  = (u16*)(ws + OFF_PM16);
    u16*   bcf       = (u16*)(ws + OFF_BCF);
    float* btot      = ws + OFF_BTOT;
    float* exs       = ws + OFF_EX;
    float* denom     = ws + OFF_DEN;
    float* agg       = ws + OFF_AGG;
    int*   count     = (int*)(ws + OFF_CNT);
    int*   cursor    = (int*)(ws + OFF_CUR);
    int*   perm      = (int*)(ws + OFF_PERM);
    int*   dsts      = (int*)(ws + OFF_DST);
    int*   srcs      = (int*)(ws + OFF_SRC);
    u16*   ewfrag    = (u16*)(ws + OFF_EWF);
    u16*   msgfrag   = (u16*)(ws + OFF_MWF);

    // zero denom + agg + count (contiguous)
    hipMemsetAsync(ws + OFF_DEN, 0, (size_t)(SZ_DEN + SZ_AGG + SZ_CNT) * 4, stream);

    k_prep<<<320, 256, 0, stream>>>(niW, njW, msgW, eW, nib, njb, eb,
                                    bcf, btot, ewfrag, msgfrag);
    k_node_pre<<<391, 256, 0, stream>>>(nf, bcf, pre16, premsg16);
    k_hist<<<1563, 256, 0, stream>>>(eidx, count);
    k_scan<<<1, 1024, 0, stream>>>(count, cursor);
    k_scatter<<<1563, 256, 0, stream>>>(eidx, cursor, perm, dsts, srcs);
    k_edge_logits<<<6250, 256, 0, stream>>>(ef, perm, dsts, srcs, ewfrag, pre16,
                                            btot, aproj, exs, denom);
    k_messages<<<6250, 256, 0, stream>>>(ef, perm, dsts, srcs, msgfrag, premsg16,
                                         exs, denom, agg);
    k_out<<<391, 256, 0, stream>>>(agg, count, msgb, outW, outb, (float*)d_out);
}